// Round 4
// baseline (817.167 us; speedup 1.0000x reference)
//
#include <hip/hip_runtime.h>
#include <stdint.h>
#include <stddef.h>

#define KH   512
#define DF   3072
#define EPSF 1e-5f
#define PPB  8            // positions per tile
#define ROWS 48           // PPB*6
#define NT   6            // tiles per persistent block

typedef __attribute__((ext_vector_type(4))) float f32x4;
typedef __attribute__((ext_vector_type(8))) short bf16x8;

__device__ __forceinline__ unsigned short f2bf(float f) {
  union { float f; unsigned u; } c; c.f = f;
  unsigned u = c.u;
  u += 0x7fffu + ((u >> 16) & 1u);     // RNE
  return (unsigned short)(u >> 16);
}
__device__ __forceinline__ float bf2f(unsigned short u) {
  union { unsigned u; float f; } c; c.u = ((unsigned)u) << 16;
  return c.f;
}

// Weight image, per-wave-contiguous fragment order:
//   byte addr = ((wn*32 + s)*4 + n)*1024 + (h*16 + co)*16 + e*2
// holds w'[o = wn*64+n*16+co][k' = 32s + 8h + e],
// where w' = alpha*gamma for k'<512 (s<16), beta_w*gamma for k'>=512 (s>=16).
// A wave's step-read is 4 x dwordx4, each fully coalesced (64 lanes x 16B = 1KB).
__global__ __launch_bounds__(256) void prep_w(const float* __restrict__ cw,
                                              const float* __restrict__ cb,
                                              const float* __restrict__ nw,
                                              const float* __restrict__ nb,
                                              unsigned char* __restrict__ wbt,
                                              float* __restrict__ c12) {
  const int o = blockIdx.x;
  const int t = threadIdx.x;
  const int wn = o >> 6, nn = (o >> 4) & 3, co = o & 15;
  float c1 = 0.f, c2 = 0.f;
  for (int k = t; k < KH; k += 256) {
    float w0 = cw[o * 1024 + 2 * k];
    float w1 = cw[o * 1024 + 2 * k + 1];
    float a  = w0 - w1;
    float g  = nw[k], b = nb[k];
    int s = k >> 5, kin = k & 31, h = kin >> 3, e = kin & 7;
    size_t base = (size_t)((wn * 32 + s) * 4 + nn) * 1024 + (h * 16 + co) * 16 + e * 2;
    *(unsigned short*)(wbt + base)               = f2bf(a * g);    // alpha half (s)
    *(unsigned short*)(wbt + base + 16 * 4096)   = f2bf(w1 * g);   // beta half (s+16)
    float tt = a + 6.f * w1;
    c1 += tt * b;
    c2 += tt * g;
  }
  #pragma unroll
  for (int off = 32; off >= 1; off >>= 1) {
    c1 += __shfl_xor(c1, off);
    c2 += __shfl_xor(c2, off);
  }
  __shared__ float s1[4], s2[4];
  int wid = t >> 6, lane = t & 63;
  if (lane == 0) { s1[wid] = c1; s2[wid] = c2; }
  __syncthreads();
  if (t == 0) {
    c12[o]      = s1[0] + s1[1] + s1[2] + s1[3] + cb[o];
    c12[KH + o] = s2[0] + s2[1] + s2[2] + s2[3];
  }
}

// Persistent: 512 blocks x 512 threads (8 waves), 2 blocks/CU, 6 tiles each.
// Per tile: build As(raw x bf16) -> stats/Sx -> barrier-free K-loop (B direct
// from L2, one-step register prefetch) -> in-place epilogue -> coalesced store.
__global__ __launch_bounds__(512, 4) void fused_main(
    const float* __restrict__ x,
    const unsigned char* __restrict__ wbt,
    const float* __restrict__ c12,
    float* __restrict__ out)
{
  __shared__ unsigned char As[ROWS * 1024];   // 48 KB raw-x/out panel (bf16), swizzled
  __shared__ unsigned char Sx[PPB * 1024];    // 8 KB color-sum panel
  __shared__ float st[PPB * 2];

  const int tid  = threadIdx.x;
  const int lane = tid & 63;
  const int wid  = tid >> 6;        // 0..7 : position owner AND o-slice (wn)
  const int co   = lane & 15;
  const int h    = lane >> 4;
  const int rvb  = h << 2;

  float C1r[4], C2r[4];
  #pragma unroll
  for (int n = 0; n < 4; n++) {
    int o = wid * 64 + n * 16 + co;
    C1r[n] = c12[o];
    C2r[n] = c12[KH + o];
  }

  int arow[3], ar7[3], sro[3], sr7[3];
  #pragma unroll
  for (int m = 0; m < 3; m++) {
    int row = m * 16 + co;
    arow[m] = row * 1024;  ar7[m] = row & 7;
    int rl  = row / 6;
    sro[m]  = rl * 1024;   sr7[m] = rl & 7;
  }
  const unsigned char* wbp = wbt + (size_t)wid * 32 * 4096;

  f32x4 q[12];
  {
    const float* xb = x + (size_t)blockIdx.x * NT * PPB * DF;
    #pragma unroll
    for (int i = 0; i < 12; i++) q[i] = *(const f32x4*)(xb + i * 2048 + tid * 4);
  }

  for (int t = 0; t < NT; t++) {
    const int r0 = (blockIdx.x * NT + t) * PPB;

    // ---- P2a: q -> As (raw bf16, k-major rows, XOR-swizzled 16B granules) ----
    #pragma unroll
    for (int i = 0; i < 12; i++) {
      int base = i * 2048 + tid * 4;
      int pl   = base / 3072;
      int rem  = base - pl * 3072;
      int k0   = rem / 6;
      int d0   = rem - k0 * 6;
      #pragma unroll
      for (int e = 0; e < 4; e++) {
        int d = d0 + e, k = k0;
        if (d >= 6) { d -= 6; k += 1; }
        int row  = pl * 6 + d;
        int byte = row * 1024 + ((((k >> 3) ^ (row & 7)) << 4)) + (k & 7) * 2;
        *(unsigned short*)(As + byte) = f2bf(q[i][e]);
      }
    }
    __syncthreads();                          // B1: As ready

    // ---- P2b: wave wid owns position wid: stats + color-sum panel ----
    {
      float vals[48];
      #pragma unroll
      for (int d = 0; d < 6; d++) {
        int row = wid * 6 + d;
        bf16x8 v = *(const bf16x8*)(As + row * 1024 + ((lane ^ (row & 7)) << 4));
        #pragma unroll
        for (int g = 0; g < 8; g++) vals[d * 8 + g] = bf2f((unsigned short)v[g]);
      }
      float s = 0.f, sq = 0.f;
      #pragma unroll
      for (int i = 0; i < 48; i++) { s += vals[i]; sq += vals[i] * vals[i]; }
      #pragma unroll
      for (int off = 32; off >= 1; off >>= 1) {
        s  += __shfl_xor(s,  off);
        sq += __shfl_xor(sq, off);
      }
      float mean = s * (1.f / 3072.f);
      float var  = sq * (1.f / 3072.f) - mean * mean;
      float rstd = rsqrtf(var + EPSF);
      if (lane == 0) { st[2 * wid] = mean; st[2 * wid + 1] = rstd; }
      bf16x8 sv;
      #pragma unroll
      for (int g = 0; g < 8; g++) {
        float ss = vals[g] + vals[8 + g] + vals[16 + g] + vals[24 + g] +
                   vals[32 + g] + vals[40 + g];
        sv[g] = (short)f2bf(ss);
      }
      *(bf16x8*)(Sx + wid * 1024 + ((lane ^ (wid & 7)) << 4)) = sv;
    }
    __syncthreads();                          // B2: Sx + st ready

    // ---- barrier-free K-loop: 32 steps of BK=32 ----
    f32x4 acc[3][4];
    #pragma unroll
    for (int m = 0; m < 3; m++)
      #pragma unroll
      for (int n = 0; n < 4; n++) acc[m][n] = (f32x4){0.f, 0.f, 0.f, 0.f};

    bf16x8 bvc[4], bvn[4];
    #pragma unroll
    for (int n = 0; n < 4; n++)
      bvc[n] = *(const bf16x8*)(wbp + n * 1024 + lane * 16);

    #pragma unroll 2
    for (int s = 0; s < 32; s++) {
      if (s < 31) {
        const unsigned char* p = wbp + (size_t)(s + 1) * 4096;
        #pragma unroll
        for (int n = 0; n < 4; n++)
          bvn[n] = *(const bf16x8*)(p + n * 1024 + lane * 16);
      }
      bf16x8 af[3];
      if (s < 16) {
        int g6 = s * 4 + h;
        #pragma unroll
        for (int m = 0; m < 3; m++)
          af[m] = *(const bf16x8*)(As + arow[m] + ((g6 ^ ar7[m]) << 4));
      } else {
        int g6 = (s - 16) * 4 + h;
        #pragma unroll
        for (int m = 0; m < 3; m++)
          af[m] = *(const bf16x8*)(Sx + sro[m] + ((g6 ^ sr7[m]) << 4));
      }
      #pragma unroll
      for (int m = 0; m < 3; m++)
        #pragma unroll
        for (int n = 0; n < 4; n++)
          acc[m][n] = __builtin_amdgcn_mfma_f32_16x16x32_bf16(af[m], bvc[n], acc[m][n], 0, 0, 0);
      #pragma unroll
      for (int n = 0; n < 4; n++) bvc[n] = bvn[n];
    }
    __syncthreads();                          // B3: all waves done reading As/Sx

    // ---- prefetch next tile's x (overlaps epilogue + next prologue) ----
    if (t < NT - 1) {
      const float* xb = x + (size_t)(r0 + PPB) * DF;
      #pragma unroll
      for (int i = 0; i < 12; i++) q[i] = *(const f32x4*)(xb + i * 2048 + tid * 4);
      __builtin_amdgcn_sched_barrier(0);
    }

    // ---- in-place epilogue: As[j][o] <- bf16(x + relu(h)) ----
    #pragma unroll
    for (int n = 0; n < 4; n++) {
      int o    = wid * 64 + n * 16 + co;
      int swzo = o >> 3;
      #pragma unroll
      for (int m = 0; m < 3; m++) {
        #pragma unroll
        for (int v = 0; v < 4; v++) {
          int j  = m * 16 + rvb + v;
          int pl = j / 6;
          float mean = st[2 * pl], rstd = st[2 * pl + 1];
          int byte = j * 1024 + (((swzo ^ (j & 7)) << 4)) + (o & 7) * 2;
          unsigned short rx = *(const unsigned short*)(As + byte);
          float hh = fmaxf(rstd * acc[m][n][v] + C1r[n] - mean * rstd * C2r[n], 0.f);
          *(unsigned short*)(As + byte) = f2bf(bf2f(rx) + hh);
        }
      }
    }
    __syncthreads();                          // B4: out panel complete

    // ---- readback + fully-coalesced stores (1 KB/wave/inst) ----
    {
      float* ob = out + (size_t)(r0 + wid) * DF;
      #pragma unroll
      for (int j = 0; j < 12; j++) {
        int c0 = j * 256 + lane * 4;
        int o0 = c0 / 6;
        int d0 = c0 - o0 * 6;
        f32x4 ov;
        #pragma unroll
        for (int e = 0; e < 4; e++) {
          int d = d0 + e, o = o0;
          if (d >= 6) { d -= 6; o += 1; }
          int row  = wid * 6 + d;
          int byte = row * 1024 + ((((o >> 3) ^ (row & 7)) << 4)) + (o & 7) * 2;
          ov[e] = bf2f(*(const unsigned short*)(As + byte));
        }
        *(f32x4*)(ob + c0) = ov;
      }
    }
    __syncthreads();                          // B5: As free for next tile
  }
}

extern "C" void kernel_launch(void* const* d_in, const int* in_sizes, int n_in,
                              void* d_out, int out_size, void* d_ws, size_t ws_size,
                              hipStream_t stream) {
  (void)n_in; (void)out_size; (void)ws_size;
  const float* x  = (const float*)d_in[0];
  const float* cw = (const float*)d_in[1];
  const float* cb = (const float*)d_in[2];
  const float* nw = (const float*)d_in[3];
  const float* nb = (const float*)d_in[4];
  float* out = (float*)d_out;

  unsigned char* wbt = (unsigned char*)d_ws;                    // 1 MB image
  float* c12 = (float*)((char*)d_ws + (size_t)1024 * 1024);     // 4 KB

  prep_w<<<512, 256, 0, stream>>>(cw, cb, nw, nb, wbt, c12);

  const int R = in_sizes[0] / DF;            // 24576 positions
  fused_main<<<R / (PPB * NT), 512, 0, stream>>>(x, wbt, c12, out);
}

// Round 5
// 253.804 us; speedup vs baseline: 3.2197x; 3.2197x over previous
//
#include <hip/hip_runtime.h>
#include <stdint.h>
#include <stddef.h>

#define KH   512
#define DF   3072
#define EPSF 1e-5f
#define PPB  16
#define ROWS 96           // PPB*6
#define TSS  520          // Ts row stride (floats), padded vs 512 to spread banks

typedef __attribute__((ext_vector_type(4))) float f32x4;
typedef __attribute__((ext_vector_type(8))) short bf16x8;

__device__ __forceinline__ unsigned short f2bf(float f) {
  union { float f; unsigned u; } c; c.f = f;
  unsigned u = c.u;
  u += 0x7fffu + ((u >> 16) & 1u);     // RNE
  return (unsigned short)(u >> 16);
}
__device__ __forceinline__ float bf2f(unsigned short u) {
  union { unsigned u; float f; } c; c.u = ((unsigned)u) << 16;
  return c.f;
}

// Two per-wave-contiguous weight images (each 512 KB):
//   region A (offset 0):      alpha*gamma,  region B (offset 512KB): beta_w*gamma
// For fragment f = o>>4 (wn = f>>2, nn = f&3) and k-step s (k = 32s+8h+e):
//   byte = region + (((f>>2)*16 + s)*4 + (f&3))*1024 + (h*16+co)*16 + e*2
// A wave's per-step fragment read is lane*16 within one 1 KB chunk (fully
// coalesced 64-lane dwordx4).
// Epilogue constants: C1(o) = sum_k (alpha+6bw)*beta_n + cb;  C2(o) = sum_k (alpha+6bw)*gamma.
__global__ __launch_bounds__(256) void prep_w(const float* __restrict__ cw,
                                              const float* __restrict__ cb,
                                              const float* __restrict__ nw,
                                              const float* __restrict__ nb,
                                              unsigned char* __restrict__ wbt,
                                              float* __restrict__ c12) {
  const int o = blockIdx.x;
  const int t = threadIdx.x;
  const int wn = o >> 6, nn = (o >> 4) & 3, co = o & 15;
  float c1 = 0.f, c2 = 0.f;
  for (int k = t; k < KH; k += 256) {
    float w0 = cw[o * 1024 + 2 * k];
    float w1 = cw[o * 1024 + 2 * k + 1];
    float a  = w0 - w1;
    float g  = nw[k], b = nb[k];
    int s = k >> 5, kin = k & 31, h = kin >> 3, e = kin & 7;
    size_t base = (size_t)(((wn * 16 + s) * 4 + nn)) * 1024 + (h * 16 + co) * 16 + e * 2;
    *(unsigned short*)(wbt + base)          = f2bf(a * g);    // alpha*gamma
    *(unsigned short*)(wbt + base + 524288) = f2bf(w1 * g);   // beta_w*gamma
    float tt = a + 6.f * w1;
    c1 += tt * b;
    c2 += tt * g;
  }
  #pragma unroll
  for (int off = 32; off >= 1; off >>= 1) {
    c1 += __shfl_xor(c1, off);
    c2 += __shfl_xor(c2, off);
  }
  __shared__ float s1[4], s2[4];
  int wid = t >> 6, lane = t & 63;
  if (lane == 0) { s1[wid] = c1; s2[wid] = c2; }
  __syncthreads();
  if (t == 0) {
    c12[o]      = s1[0] + s1[1] + s1[2] + s1[3] + cb[o];
    c12[KH + o] = s2[0] + s2[1] + s2[2] + s2[3];
  }
}

// Block: 16 positions (96 rows) x 512 o. 1024 threads = 16 waves (2M x 8N).
// term1: 96x512 GEMM over K=512 (raw x vs alpha*gamma), B per-wave from L2.
// term2: 16x512 GEMM over K=512 (raw xsum vs beta_w*gamma) -> Ts (f32 LDS).
// Epilogue: h = rstd*(acc1 + Ts) + C1 - mean*rstd*C2; out = x + relu(h).
__global__ __launch_bounds__(1024) void fused_main(
    const float* __restrict__ x,
    const unsigned char* __restrict__ wbt,
    const float* __restrict__ c12,
    float* __restrict__ out)
{
  __shared__ unsigned char As[ROWS * 1024];   // 96 KB raw-x panel (bf16, swizzled)
  __shared__ unsigned char Sx[PPB * 1024];    // 16 KB raw color-sum panel
  __shared__ float Ts[PPB * TSS];             // 32.5 KB term2 (f32)
  __shared__ float st[PPB * 2];

  const int tid  = threadIdx.x;
  const int lane = tid & 63;
  const int wid  = tid >> 6;     // 0..15
  const int wm   = wid >> 3;     // 0..1
  const int wn   = wid & 7;      // 0..7
  const int co   = lane & 15;
  const int h    = lane >> 4;
  const int rvb  = h << 2;
  const int r0   = blockIdx.x * PPB;

  // ---- P1: cooperative contiguous x load (16 B/lane, fully coalesced) ----
  {
    const float* xb = x + (size_t)r0 * DF;
    f32x4 q[12];
    #pragma unroll
    for (int i = 0; i < 12; i++) q[i] = *(const f32x4*)(xb + i * 4096 + tid * 4);

    // ---- P2a: scatter bf16 into As (row = pl*6+d, k-major, XOR-swizzled) ----
    #pragma unroll
    for (int i = 0; i < 12; i++) {
      int base = i * 4096 + tid * 4;
      int pl   = base / 3072;
      int rem  = base - pl * 3072;
      int k0   = rem / 6;
      int d0   = rem - k0 * 6;
      #pragma unroll
      for (int e = 0; e < 4; e++) {
        int d = d0 + e, k = k0;
        if (d >= 6) { d -= 6; k += 1; }
        int row  = pl * 6 + d;
        int byte = row * 1024 + ((((k >> 3) ^ (row & 7)) << 4)) + (k & 7) * 2;
        *(unsigned short*)(As + byte) = f2bf(q[i][e]);
      }
    }
  }
  __syncthreads();                          // B1: As ready

  // ---- P2b: wave wid owns position wid: LN stats + color-sum panel ----
  {
    float vals[48];
    #pragma unroll
    for (int d = 0; d < 6; d++) {
      int row = wid * 6 + d;
      bf16x8 v = *(const bf16x8*)(As + row * 1024 + ((lane ^ (row & 7)) << 4));
      #pragma unroll
      for (int g = 0; g < 8; g++) vals[d * 8 + g] = bf2f((unsigned short)v[g]);
    }
    float s = 0.f, sq = 0.f;
    #pragma unroll
    for (int i = 0; i < 48; i++) { s += vals[i]; sq += vals[i] * vals[i]; }
    #pragma unroll
    for (int off = 32; off >= 1; off >>= 1) {
      s  += __shfl_xor(s,  off);
      sq += __shfl_xor(sq, off);
    }
    float mean = s * (1.f / 3072.f);
    float var  = sq * (1.f / 3072.f) - mean * mean;
    float rstd = rsqrtf(var + EPSF);
    if (lane == 0) { st[2 * wid] = mean; st[2 * wid + 1] = rstd; }
    bf16x8 sv;
    #pragma unroll
    for (int g = 0; g < 8; g++) {
      float ss = vals[g] + vals[8 + g] + vals[16 + g] + vals[24 + g] +
                 vals[32 + g] + vals[40 + g];
      sv[g] = (short)f2bf(ss);
    }
    *(bf16x8*)(Sx + wid * 1024 + ((lane ^ (wid & 7)) << 4)) = sv;
  }
  __syncthreads();                          // B2: Sx + st ready

  // ---- term1: 96x512 over K=512, barrier-free, bv double-buffered ----
  f32x4 acc1[3][4];
  #pragma unroll
  for (int m = 0; m < 3; m++)
    #pragma unroll
    for (int n = 0; n < 4; n++) acc1[m][n] = (f32x4){0.f, 0.f, 0.f, 0.f};

  int arow[3], ar7[3];
  #pragma unroll
  for (int m = 0; m < 3; m++) {
    int row = wm * 48 + m * 16 + co;
    arow[m] = row * 1024;  ar7[m] = row & 7;
  }

  {
    const unsigned char* wA = wbt + (size_t)wn * 65536;
    bf16x8 bvc[4], bvn[4];
    #pragma unroll
    for (int n = 0; n < 4; n++)
      bvc[n] = *(const bf16x8*)(wA + n * 1024 + lane * 16);
    #pragma unroll 1
    for (int s = 0; s < 16; s++) {
      if (s < 15) {
        const unsigned char* p = wA + (size_t)(s + 1) * 4096;
        #pragma unroll
        for (int n = 0; n < 4; n++)
          bvn[n] = *(const bf16x8*)(p + n * 1024 + lane * 16);
      }
      int g6 = s * 4 + h;
      bf16x8 af[3];
      #pragma unroll
      for (int m = 0; m < 3; m++)
        af[m] = *(const bf16x8*)(As + arow[m] + ((g6 ^ ar7[m]) << 4));
      #pragma unroll
      for (int m = 0; m < 3; m++)
        #pragma unroll
        for (int n = 0; n < 4; n++)
          acc1[m][n] = __builtin_amdgcn_mfma_f32_16x16x32_bf16(af[m], bvc[n], acc1[m][n], 0, 0, 0);
      #pragma unroll
      for (int n = 0; n < 4; n++) bvc[n] = bvn[n];
    }
  }

  // ---- term2: 16x512 over K=512; each wave owns o-slice wid*32..+32 ----
  {
    f32x4 acc2[2];
    acc2[0] = (f32x4){0.f, 0.f, 0.f, 0.f};
    acc2[1] = (f32x4){0.f, 0.f, 0.f, 0.f};
    const int sxswz = (co & 7);
    bf16x8 b2c[2], b2n[2];
    #pragma unroll
    for (int n = 0; n < 2; n++) {
      int f = wid * 2 + n;      // fragment index o>>4
      b2c[n] = *(const bf16x8*)(wbt + 524288 +
                 (size_t)(((f >> 2) * 16) * 4 + (f & 3)) * 1024 + lane * 16);
    }
    #pragma unroll 1
    for (int s = 0; s < 16; s++) {
      if (s < 15) {
        #pragma unroll
        for (int n = 0; n < 2; n++) {
          int f = wid * 2 + n;
          b2n[n] = *(const bf16x8*)(wbt + 524288 +
                     (size_t)(((f >> 2) * 16 + (s + 1)) * 4 + (f & 3)) * 1024 + lane * 16);
        }
      }
      int g6 = s * 4 + h;
      bf16x8 a2 = *(const bf16x8*)(Sx + co * 1024 + ((g6 ^ sxswz) << 4));
      #pragma unroll
      for (int n = 0; n < 2; n++)
        acc2[n] = __builtin_amdgcn_mfma_f32_16x16x32_bf16(a2, b2c[n], acc2[n], 0, 0, 0);
      b2c[0] = b2n[0]; b2c[1] = b2n[1];
    }
    #pragma unroll
    for (int n = 0; n < 2; n++)
      #pragma unroll
      for (int v = 0; v < 4; v++)
        Ts[(rvb + v) * TSS + wid * 32 + n * 16 + co] = acc2[n][v];
  }
  __syncthreads();                          // B3: reads of As done; Ts ready

  // ---- epilogue: in-place RMW As[j][o] <- bf16(x + relu(h)) ----
  #pragma unroll
  for (int n = 0; n < 4; n++) {
    const int o    = wn * 64 + n * 16 + co;
    const float C1 = c12[o];
    const float C2 = c12[KH + o];
    const int swzo = o >> 3;
    #pragma unroll
    for (int m = 0; m < 3; m++) {
      #pragma unroll
      for (int v = 0; v < 4; v++) {
        int j  = wm * 48 + m * 16 + rvb + v;
        int pl = j / 6;
        float mean = st[2 * pl], rstd = st[2 * pl + 1];
        float t2   = Ts[pl * TSS + o];
        int byte = j * 1024 + (((swzo ^ (j & 7)) << 4)) + (o & 7) * 2;
        unsigned short rx = *(const unsigned short*)(As + byte);
        float hh = fmaxf(rstd * (acc1[m][n][v] + t2) + C1 - mean * rstd * C2, 0.f);
        *(unsigned short*)(As + byte) = f2bf(bf2f(rx) + hh);
      }
    }
  }
  __syncthreads();                          // B4: out panel complete

  // ---- readback + fully-coalesced stores (wave wid -> position wid) ----
  {
    float* ob = out + (size_t)(r0 + wid) * DF;
    #pragma unroll
    for (int jj = 0; jj < 12; jj++) {
      int c0 = jj * 256 + lane * 4;
      int o0 = c0 / 6;
      int d0 = c0 - o0 * 6;
      f32x4 ov;
      #pragma unroll
      for (int e = 0; e < 4; e++) {
        int d = d0 + e, o = o0;
        if (d >= 6) { d -= 6; o += 1; }
        int row  = wid * 6 + d;
        int byte = row * 1024 + ((((o >> 3) ^ (row & 7)) << 4)) + (o & 7) * 2;
        ov[e] = bf2f(*(const unsigned short*)(As + byte));
      }
      *(f32x4*)(ob + c0) = ov;
    }
  }
}

extern "C" void kernel_launch(void* const* d_in, const int* in_sizes, int n_in,
                              void* d_out, int out_size, void* d_ws, size_t ws_size,
                              hipStream_t stream) {
  (void)n_in; (void)out_size; (void)ws_size;
  const float* x  = (const float*)d_in[0];
  const float* cw = (const float*)d_in[1];
  const float* cb = (const float*)d_in[2];
  const float* nw = (const float*)d_in[3];
  const float* nb = (const float*)d_in[4];
  float* out = (float*)d_out;

  unsigned char* wbt = (unsigned char*)d_ws;                    // 1 MB images
  float* c12 = (float*)((char*)d_ws + (size_t)1024 * 1024);     // 4 KB

  prep_w<<<512, 256, 0, stream>>>(cw, cb, nw, nb, wbt, c12);

  const int R = in_sizes[0] / DF;            // 24576 positions
  fused_main<<<R / PPB, 1024, 0, stream>>>(x, wbt, c12, out);
}